// Round 9
// baseline (127.778 us; speedup 1.0000x reference)
//
#include <hip/hip_runtime.h>
#include <hip/hip_bf16.h>

// Problem constants
#define BB 2
#define SS 2048
#define DD 1024
#define HH 16
#define DKK 64

typedef __attribute__((ext_vector_type(4))) float  f32x4;
typedef __attribute__((ext_vector_type(8))) short  s16x8;
typedef __attribute__((ext_vector_type(4))) short  s16x4;
typedef __attribute__((ext_vector_type(4))) float  fvec4;

__device__ __forceinline__ short f2bs(float f) {
    union { __hip_bfloat16 b; short s; } u;
    u.b = __float2bfloat16(f);
    return u.s;
}

__device__ __forceinline__ void gload_lds16(const short* g, short* l) {
    __builtin_amdgcn_global_load_lds((const __attribute__((address_space(1))) void*)g,
                                     (__attribute__((address_space(3))) void*)l, 16, 0, 0);
}

// ---------------------------------------------------------------------------
// fp32 -> bf16 convert, 7 tensors in one launch (blockIdx.y selects tensor)
// ---------------------------------------------------------------------------
__global__ __launch_bounds__(256) void cvt_all(
    const float* __restrict__ q,  const float* __restrict__ k,  const float* __restrict__ v,
    const float* __restrict__ wq, const float* __restrict__ wk, const float* __restrict__ wv,
    const float* __restrict__ wo,
    short* __restrict__ qo,  short* __restrict__ ko,  short* __restrict__ vo,
    short* __restrict__ wqo, short* __restrict__ wko, short* __restrict__ wvo,
    short* __restrict__ woo)
{
    const float* src; short* dst; int n;
    switch (blockIdx.y) {
        case 0: src = q;  dst = qo;  n = BB * SS * DD; break;
        case 1: src = k;  dst = ko;  n = BB * SS * DD; break;
        case 2: src = v;  dst = vo;  n = BB * SS * DD; break;
        case 3: src = wq; dst = wqo; n = DD * DD; break;
        case 4: src = wk; dst = wko; n = DD * DD; break;
        case 5: src = wv; dst = wvo; n = DD * DD; break;
        default: src = wo; dst = woo; n = DD * DD; break;
    }
    int i = (blockIdx.x * 256 + threadIdx.x) * 8;
    const int stride = gridDim.x * 256 * 8;
    for (; i < n; i += stride) {
        fvec4 a = *(const fvec4*)&src[i];
        fvec4 b = *(const fvec4*)&src[i + 4];
        s16x8 o;
        o[0] = f2bs(a[0]); o[1] = f2bs(a[1]); o[2] = f2bs(a[2]); o[3] = f2bs(a[3]);
        o[4] = f2bs(b[0]); o[5] = f2bs(b[1]); o[6] = f2bs(b[2]); o[7] = f2bs(b[3]);
        *(s16x8*)&dst[i] = o;
    }
}

// ---------------------------------------------------------------------------
// GEMM v2 (NT), bf16: C[M,N] = (A[M,K] * Bw[N,K]^T + bias) * oscale
// 128xBN tile, BK=64, 4 waves. T2 both-sides swizzle. XCD-aware decode.
// BN=128 (NXSH=3): QKV fused.  BN=64 (NXSH=4): O-proj direct.
// ---------------------------------------------------------------------------
template<int BN, int NXSH, bool OUTF32>
__global__ __launch_bounds__(256) void gemm_nt_v2(
    const short* __restrict__ A0, const short* __restrict__ A1, const short* __restrict__ A2,
    const short* __restrict__ B0, const short* __restrict__ B1, const short* __restrict__ B2,
    const float* __restrict__ c0, const float* __restrict__ c1, const float* __restrict__ c2,
    void* __restrict__ O0, void* __restrict__ O1, void* __restrict__ O2,
    float os0, float os1, float os2,
    int ppx, int NY, int KL, int N, int K)
{
    const int d   = blockIdx.x;
    const int xcd = d & 7;
    const int s   = d >> 3;
    const int x   = s & ((1 << NXSH) - 1);
    const int pl  = s >> NXSH;
    const int panel = xcd * ppx + pl;
    const int y   = panel % NY;
    const int z   = panel / NY;

    const short* A    = z == 0 ? A0 : (z == 1 ? A1 : A2);
    const short* Bw   = z == 0 ? B0 : (z == 1 ? B1 : B2);
    const float* bias = z == 0 ? c0 : (z == 1 ? c1 : c2);
    void* Cp          = z == 0 ? O0 : (z == 1 ? O1 : O2);
    const float oscale = z == 0 ? os0 : (z == 1 ? os1 : os2);

    __shared__ short As[128][64];
    __shared__ short Bs[BN][64];

    const int tid  = threadIdx.x;
    const int lane = tid & 63;
    const int wid  = tid >> 6;
    const int r16  = lane & 15;
    const int g    = lane >> 4;
    const int m0   = y * 128;
    const int n0   = x * BN;
    constexpr int MR = 4;
    constexpr int NR = BN / 32;          // 128->4, 64->2
    const int wr   = (wid >> 1) * 64;
    const int wc   = (wid & 1) * (BN / 2);
    const int srow8 = lane >> 3;         // 0..7
    const int c8    = lane & 7;          // chunk 0..7

    f32x4 acc[MR][NR];
#pragma unroll
    for (int mi = 0; mi < MR; ++mi)
#pragma unroll
        for (int ni = 0; ni < NR; ++ni) acc[mi][ni] = (f32x4){0.f, 0.f, 0.f, 0.f};

    const int csrc = (c8 ^ srow8) * 8;   // source-swizzled chunk
    const int nk = KL >> 6;
#pragma unroll 1
    for (int kt = 0; kt < nk; ++kt) {
        const int k0 = kt * 64;
        if (kt) __syncthreads();
#pragma unroll
        for (int q = 0; q < 4; ++q) {
            const int r = wid * 32 + q * 8 + srow8;
            gload_lds16(&A[(size_t)(m0 + r) * K + k0 + csrc], &As[wid * 32 + q * 8][0]);
        }
#pragma unroll
        for (int q = 0; q < BN / 32; ++q) {
            const int r = wid * (BN / 4) + q * 8 + srow8;
            gload_lds16(&Bw[(size_t)(n0 + r) * K + k0 + csrc], &Bs[wid * (BN / 4) + q * 8][0]);
        }
        __syncthreads();   // drains vmcnt

#pragma unroll
        for (int kk = 0; kk < 2; ++kk) {
            s16x8 af[MR], bf[NR];
#pragma unroll
            for (int mi = 0; mi < MR; ++mi) {
                const int row = wr + mi * 16 + r16;
                af[mi] = *(const s16x8*)&As[row][((kk * 4 + g) ^ (row & 7)) * 8];
            }
#pragma unroll
            for (int ni = 0; ni < NR; ++ni) {
                const int row = wc + ni * 16 + r16;
                bf[ni] = *(const s16x8*)&Bs[row][((kk * 4 + g) ^ (row & 7)) * 8];
            }
#pragma unroll
            for (int mi = 0; mi < MR; ++mi)
#pragma unroll
                for (int ni = 0; ni < NR; ++ni)
                    acc[mi][ni] = __builtin_amdgcn_mfma_f32_16x16x32_bf16(
                        af[mi], bf[ni], acc[mi][ni], 0, 0, 0);
        }
    }

#pragma unroll
    for (int ni = 0; ni < NR; ++ni) {
        const int col = n0 + wc + ni * 16 + r16;
        const float bv = bias ? bias[col] : 0.f;
#pragma unroll
        for (int mi = 0; mi < MR; ++mi) {
#pragma unroll
            for (int r = 0; r < 4; ++r) {
                const int row = m0 + wr + mi * 16 + g * 4 + r;
                const float vv = (acc[mi][ni][r] + bv) * oscale;
                if constexpr (OUTF32)
                    ((float*)Cp)[(size_t)row * N + col] = vv;
                else
                    ((short*)Cp)[(size_t)row * N + col] = f2bs(vv);
            }
        }
    }
}

// ---------------------------------------------------------------------------
// Per-head V transpose: vp (head-major [bh][s][dk]) -> vT ([bh][dk][s])
// ---------------------------------------------------------------------------
__global__ __launch_bounds__(256) void mha_transpose_v(
    const short* __restrict__ vp, short* __restrict__ vT)
{
    const int st = blockIdx.x;
    const int bh = blockIdx.y;
    const short* src = vp + (size_t)bh * SS * DKK;
    short*       dst = vT + (size_t)bh * SS * DKK;
    const int tid = threadIdx.x;
#pragma unroll
    for (int i = 0; i < 2; ++i) {
        const int c  = tid + i * 256;   // 0..511
        const int dk = c >> 3;          // 0..63
        const int sc = c & 7;           // 0..7
        const int s0 = st * 64 + sc * 8;
        s16x8 v;
#pragma unroll
        for (int j = 0; j < 8; ++j) v[j] = src[(size_t)(s0 + j) * DKK + dk];
        *(s16x8*)&dst[(size_t)dk * SS + s0] = v;
    }
}

// ---------------------------------------------------------------------------
// Flash attention v4 (causal), buggy-reshape head layout.
// r8 post-mortem: dbuf pipeline was neutral -> bottleneck is the per-tile
// LDS-read redundancy: each wave read full K+V (16KB) for only 16 q-rows.
// v4: 32 q-rows/wave (2x16 sub-blocks, K/V frags read ONCE, reused for both)
// -> LDS bytes/row halved, block-tiles/CU halved (66 -> ~34).
// Block = one 128-row q-group, 512 blocks (2/CU). Balance: blocks lin and
// lin+256 (same CU under round-robin, same head) get complementary groups
// G, 15-G -> 34 tiles per CU regardless of bxp. Waves fully below a k-tile
// skip compute (wave-uniform; barriers kept). Mask on last 2 tiles.
// Double-buffered staging with counted vmcnt(4) retained.
// ---------------------------------------------------------------------------
__global__ __launch_bounds__(256, 2) void mha_attn(
    const short* __restrict__ qp, const short* __restrict__ kp,
    const short* __restrict__ vT, short* __restrict__ ctx)
{
    __shared__ short Ks[2][64][64];   // [buf][key][dk]   (chunk-swizzled)
    __shared__ short Vs[2][64][64];   // [buf][dv][key]   (chunk-swizzled)
    __shared__ short P[4][32][72];    // per-wave P, padded rows

    const int tid  = threadIdx.x;
    const int wid  = tid >> 6;
    const int lane = tid & 63;
    const int r16  = lane & 15;
    const int g    = lane >> 4;

    // decode: xcd(3) | head-sel(2) | gg(3) | half(1)
    const int lin  = blockIdx.x;          // 0..511
    const int xcd  = lin & 7;
    const int bh   = (xcd << 2) | ((lin >> 3) & 3);   // head pinned to XCD
    const int gg   = (lin >> 5) & 7;
    const int half = (lin >> 8) & 1;
    const int G    = half ? (15 - gg) : gg;           // 128-row group 0..15
    const int b    = bh >> 4;
    const int h    = bh & 15;

    const short* Qh = qp + (size_t)bh * SS * DKK;
    const short* Kh = kp + (size_t)bh * SS * DKK;
    const short* Vh = vT + (size_t)bh * SS * DKK;   // [DK][S]

    const int srow = lane >> 3;                     // 0..7
    const int csw  = (((lane & 7) ^ srow) & 7) * 8; // source-swizzled chunk
    const int r0   = wid * 16;                      // wave's staging stripe

    auto STAGE = [&](int buf, int j) {
        const int k0 = j * 64;
        const int rA = r0 + srow;
        const int rB = rA + 8;
        gload_lds16(&Kh[(size_t)(k0 + rA) * DKK + csw], &Ks[buf][r0][0]);
        gload_lds16(&Kh[(size_t)(k0 + rB) * DKK + csw], &Ks[buf][r0 + 8][0]);
        gload_lds16(&Vh[(size_t)rA * SS + k0 + csw],    &Vs[buf][r0][0]);
        gload_lds16(&Vh[(size_t)rB * SS + k0 + csw],    &Vs[buf][r0 + 8][0]);
    };

    const int qbase = G * 128;
    const int wrow  = qbase + wid * 32;   // wave's 32 rows
    const int nkt   = 2 * G + 2;

    // Q fragments: 2 sub-blocks x 2 k-halves
    s16x8 qf[2][2];
#pragma unroll
    for (int rb = 0; rb < 2; ++rb)
#pragma unroll
        for (int hh = 0; hh < 2; ++hh)
            qf[rb][hh] = *(const s16x8*)&Qh[(size_t)(wrow + rb * 16 + r16) * DKK + hh * 32 + g * 8];

    f32x4 po[2][4];
#pragma unroll
    for (int rb = 0; rb < 2; ++rb)
#pragma unroll
        for (int i = 0; i < 4; ++i) po[rb][i] = (f32x4){0.f, 0.f, 0.f, 0.f};
    float l_[2][4] = {{0.f, 0.f, 0.f, 0.f}, {0.f, 0.f, 0.f, 0.f}};

    STAGE(0, 0);   // prologue

#pragma unroll 1
    for (int j = 0; j < nkt; ++j) {
        const int cur = j & 1;
        const int k0 = j * 64;
        if (j + 1 < nkt) {
            STAGE(cur ^ 1, j + 1);
            asm volatile("s_waitcnt vmcnt(4)" ::: "memory");
        } else {
            asm volatile("s_waitcnt vmcnt(0)" ::: "memory");
        }
        __builtin_amdgcn_s_barrier();        // buf[cur] ready for all waves
        __builtin_amdgcn_sched_barrier(0);

        // wave-uniform skip: all 32 rows below this k-tile -> fully masked
        if (k0 < wrow + 32) {
            // ---- QK^T: K frags read once, reused for both row sub-blocks ----
            f32x4 sc[2][4];
            __builtin_amdgcn_s_setprio(1);
#pragma unroll
            for (int cg = 0; cg < 4; ++cg) {
                const int R  = cg * 16 + r16;
                const int sw = R & 7;
                const s16x8 kf0 = *(const s16x8*)&Ks[cur][R][((g ^ sw) & 7) * 8];
                const s16x8 kf1 = *(const s16x8*)&Ks[cur][R][(((4 + g) ^ sw) & 7) * 8];
#pragma unroll
                for (int rb = 0; rb < 2; ++rb) {
                    f32x4 tt = (f32x4){0.f, 0.f, 0.f, 0.f};
                    tt = __builtin_amdgcn_mfma_f32_16x16x32_bf16(qf[rb][0], kf0, tt, 0, 0, 0);
                    tt = __builtin_amdgcn_mfma_f32_16x16x32_bf16(qf[rb][1], kf1, tt, 0, 0, 0);
                    sc[rb][cg] = tt;
                }
            }
            __builtin_amdgcn_s_setprio(0);

            // ---- causal mask (rows span 128 -> last two tiles need it) ----
            if (j >= nkt - 2) {
#pragma unroll
                for (int rb = 0; rb < 2; ++rb)
#pragma unroll
                    for (int cg = 0; cg < 4; ++cg)
#pragma unroll
                        for (int r = 0; r < 4; ++r)
                            if (k0 + cg * 16 + r16 > wrow + rb * 16 + g * 4 + r)
                                sc[rb][cg][r] = -1e9f;
            }
            // ---- softmax-lite ----
#pragma unroll
            for (int rb = 0; rb < 2; ++rb)
#pragma unroll
                for (int cg = 0; cg < 4; ++cg)
#pragma unroll
                    for (int r = 0; r < 4; ++r) {
                        const float p = __expf(sc[rb][cg][r]);
                        l_[rb][r] += p;
                        P[wid][rb * 16 + g * 4 + r][cg * 16 + r16] = f2bs(p);
                    }
            // same-wave write->read
            s16x8 pf[2][2];
#pragma unroll
            for (int rb = 0; rb < 2; ++rb) {
                pf[rb][0] = *(const s16x8*)&P[wid][rb * 16 + r16][g * 8];
                pf[rb][1] = *(const s16x8*)&P[wid][rb * 16 + r16][32 + g * 8];
            }
            // ---- PV: V frags read once, reused for both row sub-blocks ----
            __builtin_amdgcn_s_setprio(1);
#pragma unroll
            for (int dg = 0; dg < 4; ++dg) {
                const int Rv = dg * 16 + r16;
                const int sw = Rv & 7;
                const s16x8 vf0 = *(const s16x8*)&Vs[cur][Rv][((g ^ sw) & 7) * 8];
                const s16x8 vf1 = *(const s16x8*)&Vs[cur][Rv][(((4 + g) ^ sw) & 7) * 8];
#pragma unroll
                for (int rb = 0; rb < 2; ++rb) {
                    po[rb][dg] = __builtin_amdgcn_mfma_f32_16x16x32_bf16(pf[rb][0], vf0, po[rb][dg], 0, 0, 0);
                    po[rb][dg] = __builtin_amdgcn_mfma_f32_16x16x32_bf16(pf[rb][1], vf1, po[rb][dg], 0, 0, 0);
                }
            }
            __builtin_amdgcn_s_setprio(0);
        }

        // ---- tile end: LDS reads retired, then release the buffer ----
        __builtin_amdgcn_sched_barrier(0);
        asm volatile("s_waitcnt lgkmcnt(0)" ::: "memory");
        __builtin_amdgcn_s_barrier();
    }

    // ---- epilogue ----
#pragma unroll
    for (int rb = 0; rb < 2; ++rb) {
#pragma unroll
        for (int r = 0; r < 4; ++r) {
#pragma unroll
            for (int off = 1; off < 16; off <<= 1)
                l_[rb][r] += __shfl_xor(l_[rb][r], off);
        }
#pragma unroll
        for (int dg = 0; dg < 4; ++dg)
#pragma unroll
            for (int r = 0; r < 4; ++r) {
                const int srw = wrow + rb * 16 + g * 4 + r;
                const float v = po[rb][dg][r] * __builtin_amdgcn_rcpf(l_[rb][r]);
                ctx[((size_t)(b * SS + srw)) * DD + h * 64 + dg * 16 + r16] = f2bs(v);
            }
    }
}

// ---------------------------------------------------------------------------
extern "C" void kernel_launch(void* const* d_in, const int* in_sizes, int n_in,
                              void* d_out, int out_size, void* d_ws, size_t ws_size,
                              hipStream_t stream) {
    const float* query = (const float*)d_in[0];
    const float* key   = (const float*)d_in[1];
    const float* value = (const float*)d_in[2];
    // d_in[3] = mask (causal tril) -- implemented analytically
    const float* Wq = (const float*)d_in[4];
    const float* bq = (const float*)d_in[5];
    const float* Wk = (const float*)d_in[6];
    const float* bk = (const float*)d_in[7];
    const float* Wv = (const float*)d_in[8];
    const float* bv = (const float*)d_in[9];
    const float* Wo = (const float*)d_in[10];
    const float* bo = (const float*)d_in[11];
    float* out = (float*)d_out;

    const size_t elems = (size_t)BB * SS * DD;   // 4M
    const size_t wel   = (size_t)DD * DD;        // 1M
    short* qx  = (short*)d_ws;        // bf16 inputs
    short* kx  = qx + elems;
    short* vx  = kx + elems;
    short* wqx = vx + elems;          // bf16 weights
    short* wkx = wqx + wel;
    short* wvx = wkx + wel;
    short* wox = wvx + wel;
    short* qp  = wox + wel;           // projections
    short* kp  = qp + elems;
    short* vp  = kp + elems;
    // aliases (lifetime-disjoint):
    short* vT  = qx;                  // qx dead after QKV GEMM
    short* ctx = vx;                  // vx dead after QKV GEMM

    // 1) convert everything to bf16
    cvt_all<<<dim3(1024, 7), 256, 0, stream>>>(query, key, value, Wq, Wk, Wv, Wo,
                                               qx, kx, vx, wqx, wkx, wvx, wox);
    // 2) fused Q/K/V projections; 1/sqrt(DK) folded into Q
    gemm_nt_v2<128, 3, false><<<dim3(768), 256, 0, stream>>>(
        qx, kx, vx, wqx, wkx, wvx, bq, bk, bv, qp, kp, vp,
        0.125f, 1.0f, 1.0f, /*ppx=*/12, /*NY=*/32, /*KL=*/1024, DD, DD);
    // 3) V transpose per head (vT = qx region)
    mha_transpose_v<<<dim3(SS / 64, BB * HH), 256, 0, stream>>>(vp, vT);
    // 4) attention -> ctx (= vx region), 32 rows/wave, complementary-cost grid
    mha_attn<<<dim3(512), 256, 0, stream>>>(qp, kp, vT, ctx);
    // 5) output projection, direct (BM=128, BN=64 -> 512 blocks = 2/CU)
    gemm_nt_v2<64, 4, true><<<dim3(512), 256, 0, stream>>>(
        ctx, ctx, ctx, wox, wox, wox, bo, bo, bo, out, out, out,
        1.0f, 1.0f, 1.0f, /*ppx=*/4, /*NY=*/32, /*KL=*/1024, DD, DD);
}

// Round 10
// 120.340 us; speedup vs baseline: 1.0618x; 1.0618x over previous
//
#include <hip/hip_runtime.h>
#include <hip/hip_bf16.h>

// Problem constants
#define BB 2
#define SS 2048
#define DD 1024
#define HH 16
#define DKK 64

typedef __attribute__((ext_vector_type(4))) float  f32x4;
typedef __attribute__((ext_vector_type(8))) short  s16x8;
typedef __attribute__((ext_vector_type(4))) short  s16x4;
typedef __attribute__((ext_vector_type(4))) float  fvec4;
typedef __attribute__((ext_vector_type(2))) unsigned int u32x2;

__device__ __forceinline__ short f2bs(float f) {
    union { __hip_bfloat16 b; short s; } u;
    u.b = __float2bfloat16(f);
    return u.s;
}

// pack two f32 -> u32 of two bf16 (v_cvt_pk_bf16_f32; no builtin on gfx950)
__device__ __forceinline__ unsigned cvtpk(float lo, float hi) {
    unsigned r;
    asm("v_cvt_pk_bf16_f32 %0, %1, %2" : "=v"(r) : "v"(lo), "v"(hi));
    return r;
}

__device__ __forceinline__ void gload_lds16(const short* g, short* l) {
    __builtin_amdgcn_global_load_lds((const __attribute__((address_space(1))) void*)g,
                                     (__attribute__((address_space(3))) void*)l, 16, 0, 0);
}

// ---------------------------------------------------------------------------
// fp32 -> bf16 convert, 7 tensors in one launch (blockIdx.y selects tensor)
// ---------------------------------------------------------------------------
__global__ __launch_bounds__(256) void cvt_all(
    const float* __restrict__ q,  const float* __restrict__ k,  const float* __restrict__ v,
    const float* __restrict__ wq, const float* __restrict__ wk, const float* __restrict__ wv,
    const float* __restrict__ wo,
    short* __restrict__ qo,  short* __restrict__ ko,  short* __restrict__ vo,
    short* __restrict__ wqo, short* __restrict__ wko, short* __restrict__ wvo,
    short* __restrict__ woo)
{
    const float* src; short* dst; int n;
    switch (blockIdx.y) {
        case 0: src = q;  dst = qo;  n = BB * SS * DD; break;
        case 1: src = k;  dst = ko;  n = BB * SS * DD; break;
        case 2: src = v;  dst = vo;  n = BB * SS * DD; break;
        case 3: src = wq; dst = wqo; n = DD * DD; break;
        case 4: src = wk; dst = wko; n = DD * DD; break;
        case 5: src = wv; dst = wvo; n = DD * DD; break;
        default: src = wo; dst = woo; n = DD * DD; break;
    }
    int i = (blockIdx.x * 256 + threadIdx.x) * 8;
    const int stride = gridDim.x * 256 * 8;
    for (; i < n; i += stride) {
        fvec4 a = *(const fvec4*)&src[i];
        fvec4 b = *(const fvec4*)&src[i + 4];
        s16x8 o;
        o[0] = f2bs(a[0]); o[1] = f2bs(a[1]); o[2] = f2bs(a[2]); o[3] = f2bs(a[3]);
        o[4] = f2bs(b[0]); o[5] = f2bs(b[1]); o[6] = f2bs(b[2]); o[7] = f2bs(b[3]);
        *(s16x8*)&dst[i] = o;
    }
}

// ---------------------------------------------------------------------------
// GEMM v2 (NT), bf16: C[M,N] = (A[M,K] * Bw[N,K]^T + bias) * oscale
// 128xBN tile, BK=64, 4 waves. T2 both-sides swizzle. XCD-aware decode.
// BN=128 (NXSH=3): QKV fused.  BN=64 (NXSH=4): O-proj direct.
// ---------------------------------------------------------------------------
template<int BN, int NXSH, bool OUTF32>
__global__ __launch_bounds__(256) void gemm_nt_v2(
    const short* __restrict__ A0, const short* __restrict__ A1, const short* __restrict__ A2,
    const short* __restrict__ B0, const short* __restrict__ B1, const short* __restrict__ B2,
    const float* __restrict__ c0, const float* __restrict__ c1, const float* __restrict__ c2,
    void* __restrict__ O0, void* __restrict__ O1, void* __restrict__ O2,
    float os0, float os1, float os2,
    int ppx, int NY, int KL, int N, int K)
{
    const int d   = blockIdx.x;
    const int xcd = d & 7;
    const int s   = d >> 3;
    const int x   = s & ((1 << NXSH) - 1);
    const int pl  = s >> NXSH;
    const int panel = xcd * ppx + pl;
    const int y   = panel % NY;
    const int z   = panel / NY;

    const short* A    = z == 0 ? A0 : (z == 1 ? A1 : A2);
    const short* Bw   = z == 0 ? B0 : (z == 1 ? B1 : B2);
    const float* bias = z == 0 ? c0 : (z == 1 ? c1 : c2);
    void* Cp          = z == 0 ? O0 : (z == 1 ? O1 : O2);
    const float oscale = z == 0 ? os0 : (z == 1 ? os1 : os2);

    __shared__ short As[128][64];
    __shared__ short Bs[BN][64];

    const int tid  = threadIdx.x;
    const int lane = tid & 63;
    const int wid  = tid >> 6;
    const int r16  = lane & 15;
    const int g    = lane >> 4;
    const int m0   = y * 128;
    const int n0   = x * BN;
    constexpr int MR = 4;
    constexpr int NR = BN / 32;          // 128->4, 64->2
    const int wr   = (wid >> 1) * 64;
    const int wc   = (wid & 1) * (BN / 2);
    const int srow8 = lane >> 3;         // 0..7
    const int c8    = lane & 7;          // chunk 0..7

    f32x4 acc[MR][NR];
#pragma unroll
    for (int mi = 0; mi < MR; ++mi)
#pragma unroll
        for (int ni = 0; ni < NR; ++ni) acc[mi][ni] = (f32x4){0.f, 0.f, 0.f, 0.f};

    const int csrc = (c8 ^ srow8) * 8;   // source-swizzled chunk
    const int nk = KL >> 6;
#pragma unroll 1
    for (int kt = 0; kt < nk; ++kt) {
        const int k0 = kt * 64;
        if (kt) __syncthreads();
#pragma unroll
        for (int q = 0; q < 4; ++q) {
            const int r = wid * 32 + q * 8 + srow8;
            gload_lds16(&A[(size_t)(m0 + r) * K + k0 + csrc], &As[wid * 32 + q * 8][0]);
        }
#pragma unroll
        for (int q = 0; q < BN / 32; ++q) {
            const int r = wid * (BN / 4) + q * 8 + srow8;
            gload_lds16(&Bw[(size_t)(n0 + r) * K + k0 + csrc], &Bs[wid * (BN / 4) + q * 8][0]);
        }
        __syncthreads();   // drains vmcnt

#pragma unroll
        for (int kk = 0; kk < 2; ++kk) {
            s16x8 af[MR], bf[NR];
#pragma unroll
            for (int mi = 0; mi < MR; ++mi) {
                const int row = wr + mi * 16 + r16;
                af[mi] = *(const s16x8*)&As[row][((kk * 4 + g) ^ (row & 7)) * 8];
            }
#pragma unroll
            for (int ni = 0; ni < NR; ++ni) {
                const int row = wc + ni * 16 + r16;
                bf[ni] = *(const s16x8*)&Bs[row][((kk * 4 + g) ^ (row & 7)) * 8];
            }
#pragma unroll
            for (int mi = 0; mi < MR; ++mi)
#pragma unroll
                for (int ni = 0; ni < NR; ++ni)
                    acc[mi][ni] = __builtin_amdgcn_mfma_f32_16x16x32_bf16(
                        af[mi], bf[ni], acc[mi][ni], 0, 0, 0);
        }
    }

#pragma unroll
    for (int ni = 0; ni < NR; ++ni) {
        const int col = n0 + wc + ni * 16 + r16;
        const float bv = bias ? bias[col] : 0.f;
#pragma unroll
        for (int mi = 0; mi < MR; ++mi) {
#pragma unroll
            for (int r = 0; r < 4; ++r) {
                const int row = m0 + wr + mi * 16 + g * 4 + r;
                const float vv = (acc[mi][ni][r] + bv) * oscale;
                if constexpr (OUTF32)
                    ((float*)Cp)[(size_t)row * N + col] = vv;
                else
                    ((short*)Cp)[(size_t)row * N + col] = f2bs(vv);
            }
        }
    }
}

// ---------------------------------------------------------------------------
// Per-head V transpose: vp (head-major [bh][s][dk]) -> vT ([bh][dk][s])
// ---------------------------------------------------------------------------
__global__ __launch_bounds__(256) void mha_transpose_v(
    const short* __restrict__ vp, short* __restrict__ vT)
{
    const int st = blockIdx.x;
    const int bh = blockIdx.y;
    const short* src = vp + (size_t)bh * SS * DKK;
    short*       dst = vT + (size_t)bh * SS * DKK;
    const int tid = threadIdx.x;
#pragma unroll
    for (int i = 0; i < 2; ++i) {
        const int c  = tid + i * 256;   // 0..511
        const int dk = c >> 3;          // 0..63
        const int sc = c & 7;           // 0..7
        const int s0 = st * 64 + sc * 8;
        s16x8 v;
#pragma unroll
        for (int j = 0; j < 8; ++j) v[j] = src[(size_t)(s0 + j) * DKK + dk];
        *(s16x8*)&dst[(size_t)dk * SS + s0] = v;
    }
}

// ---------------------------------------------------------------------------
// Flash attention v5 (causal): r5 structure (single-buffered LDS K/V,
// 64-row groups paired (bxp,31-bxp) -> 33 tiles/block guaranteed, head
// pinned to XCD) + SWAPPED QK^T (T12):
//   QK computes mfma(K,Q) -> score tile transposed: lane owns q = lane&15,
//   keys cg*16+g*4+r. Row-sum is lane-local (one scalar), causal compare
//   lane-local, and P is emitted in final A-frag layout with 2 cvt_pk +
//   1 ds_write_b64 per cg (replaces 16 scalar u16 writes + 16 f2bs).
//   PV unchanged (A=P from LDS, B=V from Vs). Epilogue: 2 shfl_xor + 4 shfl.
// Fragment maps (m89-verified): A row=l&15, k=(l>>4)*8+j; B col=l&15,
// k=(l>>4)*8+j; C/D col=l&15, row=(l>>4)*4+r.
// ---------------------------------------------------------------------------
__global__ __launch_bounds__(256, 2) void mha_attn(
    const short* __restrict__ qp, const short* __restrict__ kp,
    const short* __restrict__ vT, short* __restrict__ ctx)
{
    __shared__ short Ks[64][64];     // [key][dk]   (chunk-swizzled)
    __shared__ short Vs[64][64];     // [dv][key]   (chunk-swizzled)
    __shared__ short P[4][16][72];   // per-wave P[q][key], padded rows

    const int tid  = threadIdx.x;
    const int wid  = tid >> 6;
    const int lane = tid & 63;
    const int r16  = lane & 15;
    const int g    = lane >> 4;

    const int bh  = blockIdx.x;   // 0..31 -> XCD = bh%8 (head pinned to XCD)
    const int bxp = blockIdx.y;   // 0..15
    const int b   = bh >> 4;
    const int h   = bh & 15;

    const short* Qh = qp + (size_t)bh * SS * DKK;
    const short* Kh = kp + (size_t)bh * SS * DKK;
    const short* Vh = vT + (size_t)bh * SS * DKK;   // [DK][S]

    const int srow = lane >> 3;                     // 0..7
    const int csw  = (((lane & 7) ^ srow) & 7) * 8; // source-swizzled chunk
    const int r0   = wid * 16;                      // wave's staging stripe

#pragma unroll 1
    for (int t = 0; t < 2; ++t) {
        const int grp = t ? (31 - bxp) : bxp;     // 64-row q-group index
        const int qr0 = grp * 64 + wid * 16;
        const int nkt = grp + 1;

        // Q fragments (row-frag of Q == col-frag of Q^T: same per-lane data)
        const s16x8 qf0 = *(const s16x8*)&Qh[(size_t)(qr0 + r16) * DKK + g * 8];
        const s16x8 qf1 = *(const s16x8*)&Qh[(size_t)(qr0 + r16) * DKK + 32 + g * 8];

        f32x4 po[4];
#pragma unroll
        for (int i = 0; i < 4; ++i) po[i] = (f32x4){0.f, 0.f, 0.f, 0.f};
        float lsum = 0.f;   // partial softmax denom for q = r16

#pragma unroll 1
        for (int j = 0; j < nkt; ++j) {
            const int k0 = j * 64;
            __syncthreads();   // protect Ks/Vs (and P across groups)
            // ---- stage K and Vt tiles (16KB), source-swizzled ----
            {
                const int rowA = r0 + srow;
                const int rowB = rowA + 8;
                gload_lds16(&Kh[(size_t)(k0 + rowA) * DKK + csw], &Ks[r0][0]);
                gload_lds16(&Kh[(size_t)(k0 + rowB) * DKK + csw], &Ks[r0 + 8][0]);
                gload_lds16(&Vh[(size_t)rowA * SS + k0 + csw], &Vs[r0][0]);
                gload_lds16(&Vh[(size_t)rowB * SS + k0 + csw], &Vs[r0 + 8][0]);
            }
            __syncthreads();   // drain vmcnt: tiles ready

            // ---- swapped QK^T: T[key][q] = mfma(A=K, B=Q) ----
            f32x4 sc[4];
            __builtin_amdgcn_s_setprio(1);
#pragma unroll
            for (int cg = 0; cg < 4; ++cg) {
                const int R  = cg * 16 + r16;
                const int sw = R & 7;
                const s16x8 kf0 = *(const s16x8*)&Ks[R][((g ^ sw) & 7) * 8];
                const s16x8 kf1 = *(const s16x8*)&Ks[R][(((4 + g) ^ sw) & 7) * 8];
                f32x4 tt = (f32x4){0.f, 0.f, 0.f, 0.f};
                tt = __builtin_amdgcn_mfma_f32_16x16x32_bf16(kf0, qf0, tt, 0, 0, 0);
                tt = __builtin_amdgcn_mfma_f32_16x16x32_bf16(kf1, qf1, tt, 0, 0, 0);
                sc[cg] = tt;   // lane: q = r16, keys = k0 + cg*16 + g*4 + r
            }
            __builtin_amdgcn_s_setprio(0);

            // ---- causal mask (diag tile): key > q-row ----
            if (j == nkt - 1) {
#pragma unroll
                for (int cg = 0; cg < 4; ++cg)
#pragma unroll
                    for (int r = 0; r < 4; ++r)
                        if (k0 + cg * 16 + g * 4 + r > qr0 + r16) sc[cg][r] = -1e9f;
            }
            // ---- softmax-lite: exp, lane-local sum, packed P write ----
#pragma unroll
            for (int cg = 0; cg < 4; ++cg) {
                const float p0 = __expf(sc[cg][0]);
                const float p1 = __expf(sc[cg][1]);
                const float p2 = __expf(sc[cg][2]);
                const float p3 = __expf(sc[cg][3]);
                lsum += (p0 + p1) + (p2 + p3);
                u32x2 w;
                w[0] = cvtpk(p0, p1);
                w[1] = cvtpk(p2, p3);
                *(u32x2*)&P[wid][r16][cg * 16 + g * 4] = w;   // ds_write_b64
            }
            // same-wave write->read: compiler inserts lgkmcnt wait
            const s16x8 pf0 = *(const s16x8*)&P[wid][r16][g * 8];
            const s16x8 pf1 = *(const s16x8*)&P[wid][r16][32 + g * 8];

            // ---- PV: A = P, B = V (unchanged) ----
            __builtin_amdgcn_s_setprio(1);
#pragma unroll
            for (int dg = 0; dg < 4; ++dg) {
                const int Rv = dg * 16 + r16;
                const int sw = Rv & 7;
                const s16x8 vf0 = *(const s16x8*)&Vs[Rv][((g ^ sw) & 7) * 8];
                const s16x8 vf1 = *(const s16x8*)&Vs[Rv][(((4 + g) ^ sw) & 7) * 8];
                po[dg] = __builtin_amdgcn_mfma_f32_16x16x32_bf16(pf0, vf0, po[dg], 0, 0, 0);
                po[dg] = __builtin_amdgcn_mfma_f32_16x16x32_bf16(pf1, vf1, po[dg], 0, 0, 0);
            }
            __builtin_amdgcn_s_setprio(0);
        }

        // ---- epilogue: finish denom, fetch per-row inverse, store ----
        lsum += __shfl_xor(lsum, 16);
        lsum += __shfl_xor(lsum, 32);   // lane now holds total for q = r16
        const float linv = __builtin_amdgcn_rcpf(lsum);
        float rowinv[4];
#pragma unroll
        for (int r = 0; r < 4; ++r)
            rowinv[r] = __shfl(linv, g * 4 + r);   // lane (g*4+r) has q = g*4+r
#pragma unroll
        for (int dg = 0; dg < 4; ++dg)
#pragma unroll
            for (int r = 0; r < 4; ++r) {
                const int srw = qr0 + g * 4 + r;
                const float v = po[dg][r] * rowinv[r];
                ctx[((size_t)(b * SS + srw)) * DD + h * 64 + dg * 16 + r16] = f2bs(v);
            }
    }
}

// ---------------------------------------------------------------------------
extern "C" void kernel_launch(void* const* d_in, const int* in_sizes, int n_in,
                              void* d_out, int out_size, void* d_ws, size_t ws_size,
                              hipStream_t stream) {
    const float* query = (const float*)d_in[0];
    const float* key   = (const float*)d_in[1];
    const float* value = (const float*)d_in[2];
    // d_in[3] = mask (causal tril) -- implemented analytically
    const float* Wq = (const float*)d_in[4];
    const float* bq = (const float*)d_in[5];
    const float* Wk = (const float*)d_in[6];
    const float* bk = (const float*)d_in[7];
    const float* Wv = (const float*)d_in[8];
    const float* bv = (const float*)d_in[9];
    const float* Wo = (const float*)d_in[10];
    const float* bo = (const float*)d_in[11];
    float* out = (float*)d_out;

    const size_t elems = (size_t)BB * SS * DD;   // 4M
    const size_t wel   = (size_t)DD * DD;        // 1M
    short* qx  = (short*)d_ws;        // bf16 inputs
    short* kx  = qx + elems;
    short* vx  = kx + elems;
    short* wqx = vx + elems;          // bf16 weights
    short* wkx = wqx + wel;
    short* wvx = wkx + wel;
    short* wox = wvx + wel;
    short* qp  = wox + wel;           // projections
    short* kp  = qp + elems;
    short* vp  = kp + elems;
    // aliases (lifetime-disjoint):
    short* vT  = qx;                  // qx dead after QKV GEMM
    short* ctx = vx;                  // vx dead after QKV GEMM

    // 1) convert everything to bf16
    cvt_all<<<dim3(1024, 7), 256, 0, stream>>>(query, key, value, Wq, Wk, Wv, Wo,
                                               qx, kx, vx, wqx, wkx, wvx, wox);
    // 2) fused Q/K/V projections; 1/sqrt(DK) folded into Q
    gemm_nt_v2<128, 3, false><<<dim3(768), 256, 0, stream>>>(
        qx, kx, vx, wqx, wkx, wvx, bq, bk, bv, qp, kp, vp,
        0.125f, 1.0f, 1.0f, /*ppx=*/12, /*NY=*/32, /*KL=*/1024, DD, DD);
    // 3) V transpose per head (vT = qx region)
    mha_transpose_v<<<dim3(SS / 64, BB * HH), 256, 0, stream>>>(vp, vT);
    // 4) attention -> ctx (= vx region): r5 structure + swapped-QK softmax
    mha_attn<<<dim3(BB * HH, 16), 256, 0, stream>>>(qp, kp, vT, ctx);
    // 5) output projection, direct (BM=128, BN=64 -> 512 blocks = 2/CU)
    gemm_nt_v2<64, 4, true><<<dim3(512), 256, 0, stream>>>(
        ctx, ctx, ctx, wox, wox, wox, bo, bo, bo, out, out, out,
        1.0f, 1.0f, 1.0f, /*ppx=*/4, /*NY=*/32, /*KL=*/1024, DD, DD);
}